// Round 6
// baseline (214.349 us; speedup 1.0000x reference)
//
#include <hip/hip_runtime.h>
#include <math.h>

typedef __bf16 b16x8 __attribute__((ext_vector_type(8)));
typedef float  f32x4 __attribute__((ext_vector_type(4)));

#define B_    8
#define CIN_  64
#define COUT_ 64
#define Hs    96
#define Ws    96
#define PLANE (Hs*Ws)        // 9216
#define IMG   (CIN_*PLANE)   // 589824
#define NP    (B_*PLANE)     // 73728
#define NBLK  (NP/64)        // 1152

__device__ __forceinline__ int swz(int bid) { return (bid & 7) * (NBLK / 8) + (bid >> 3); }

// Pre-swizzle weights into per-lane MFMA A-fragment order (bf16).
// wAB flat: i = k*4096 + ks*2048 + mt*512 + lane*8 + e
//   o = mt*16 + (lane&15); c = ks*32 + (lane>>4)*8 + e; val = weight[o*576 + c*9 + k]
// wAO flat: j = t*2048 + ks*1024 + mt*512 + lane*8 + e
//   ch = mt*16 + (lane&15); c likewise; val = w_off[ch*576 + c*9 + t] (0 for ch>=27)
__global__ void prep(const float* __restrict__ weight, const float* __restrict__ w_off,
                     __bf16* __restrict__ wAB, __bf16* __restrict__ wAO) {
    int i = blockIdx.x * 256 + threadIdx.x;
    if (i < 36864) {
        int e = i & 7, lane = (i >> 3) & 63, mt = (i >> 9) & 3, ks = (i >> 11) & 1, k = i >> 12;
        int o = mt * 16 + (lane & 15);
        int c = ks * 32 + ((lane >> 4) << 3) + e;
        wAB[i] = (__bf16)weight[o * 576 + c * 9 + k];
    }
    if (i < 18432) {
        int e = i & 7, lane = (i >> 3) & 63, mt = (i >> 9) & 1, ks = (i >> 10) & 1, t = i >> 11;
        int ch = mt * 16 + (lane & 15);
        int c  = ks * 32 + ((lane >> 4) << 3) + e;
        wAO[i] = (ch < 27) ? (__bf16)w_off[ch * 576 + c * 9 + t] : (__bf16)(0.f);
    }
}

// One fused kernel. Block = 64 px x 4 waves.
// Phase A: om[27][64] via MFMA (M=32 padded, K=576), result -> LDS.
// Phase B: main conv via MFMA (M=64, K=576), sampled bf16 tile in dbuf LDS.
// Gather loads are explicitly batched into register arrays so ALL issues
// precede ALL uses -> one vmcnt batch per tap (was 16 serial round-trips
// at VGPR_Count=64). __launch_bounds__(256,3) caps VGPR at ~170.
__global__ __launch_bounds__(256, 3)
void deform_mfma(const float* __restrict__ x,
                 const __bf16* __restrict__ wAO,
                 const float* __restrict__ b_off,
                 const __bf16* __restrict__ wAB,
                 const float* __restrict__ bias,
                 float* __restrict__ out) {
    __shared__ __align__(16) __bf16 sS[2 * 4608];   // 18432 B
    __shared__ float omL[27 * 64];                  //  6912 B

    int tid  = threadIdx.x;
    int lane = tid & 63;
    int px   = lane;
    int g    = __builtin_amdgcn_readfirstlane(tid >> 6);
    int n    = lane & 15;
    int kg   = lane >> 4;

    int pg0  = swz(blockIdx.x) * 64;
    int b    = pg0 / PLANE;
    int rblk = pg0 - b * PLANE;
    int rr   = rblk + px;
    int h    = rr / Ws, w = rr - h * Ws;
    const float* xb = x + b * IMG;
    const float* xg = xb + (g * 16) * PLANE;   // this wave stages c = g*16 .. g*16+15

    const b16x8* wAOv = (const b16x8*)wAO;
    const b16x8* wABv = (const b16x8*)wAB;

    // ---------------- Phase A: offset conv via MFMA ----------------
    f32x4 accA0 = {0.f, 0.f, 0.f, 0.f};
    f32x4 accA1 = {0.f, 0.f, 0.f, 0.f};
#pragma unroll 1
    for (int t = 0; t < 9; ++t) {
        b16x8 af0 = wAOv[((t * 2 + 0) * 2 + 0) * 64 + lane];
        b16x8 af1 = wAOv[((t * 2 + 0) * 2 + 1) * 64 + lane];
        b16x8 af2 = wAOv[((t * 2 + 1) * 2 + 0) * 64 + lane];
        b16x8 af3 = wAOv[((t * 2 + 1) * 2 + 1) * 64 + lane];

        // stage x-patch tile (zero-padded) as bf16 [px][c] — batched loads
        int ky = t / 3, kx = t - ky * 3;
        int yy = h - 1 + ky, xx = w - 1 + kx;
        float msk = (yy >= 0 && yy < Hs && xx >= 0 && xx < Ws) ? 1.f : 0.f;
        int idx = min(max(yy, 0), Hs - 1) * Ws + min(max(xx, 0), Ws - 1);
        const float* xp = xg + idx;
        float cv[16];
#pragma unroll
        for (int i = 0; i < 16; ++i) cv[i] = xp[i * PLANE];
        b16x8 v0, v1;
#pragma unroll
        for (int i = 0; i < 8; ++i)  v0[i] = (__bf16)(cv[i] * msk);
#pragma unroll
        for (int i = 0; i < 8; ++i)  v1[i] = (__bf16)(cv[i + 8] * msk);
        int wb = (t & 1) * 4608 + px * 72 + g * 16;
        *(b16x8*)&sS[wb]     = v0;
        *(b16x8*)&sS[wb + 8] = v1;
        __syncthreads();

        int rbase = (t & 1) * 4608 + (g * 16 + n) * 72 + kg * 8;
        b16x8 bf0 = *(const b16x8*)&sS[rbase];
        b16x8 bf1 = *(const b16x8*)&sS[rbase + 32];
        accA0 = __builtin_amdgcn_mfma_f32_16x16x32_bf16(af0, bf0, accA0, 0, 0, 0);
        accA1 = __builtin_amdgcn_mfma_f32_16x16x32_bf16(af1, bf0, accA1, 0, 0, 0);
        accA0 = __builtin_amdgcn_mfma_f32_16x16x32_bf16(af2, bf1, accA0, 0, 0, 0);
        accA1 = __builtin_amdgcn_mfma_f32_16x16x32_bf16(af3, bf1, accA1, 0, 0, 0);
    }
    // write om (+b_off) to LDS: C layout row=(kg*4+r), col=n
#pragma unroll
    for (int rg = 0; rg < 4; ++rg) {
        int ch = kg * 4 + rg;
        omL[ch * 64 + g * 16 + n] = accA0[rg] + b_off[ch];
    }
#pragma unroll
    for (int rg = 0; rg < 4; ++rg) {
        int ch = 16 + kg * 4 + rg;
        if (ch < 27) omL[ch * 64 + g * 16 + n] = accA1[rg] + b_off[ch];
    }
    __syncthreads();

    // ---------------- Phase B: sampling + main conv via MFMA ----------------
    f32x4 acc0 = {0.f, 0.f, 0.f, 0.f};
    f32x4 acc1 = {0.f, 0.f, 0.f, 0.f};
    f32x4 acc2 = {0.f, 0.f, 0.f, 0.f};
    f32x4 acc3 = {0.f, 0.f, 0.f, 0.f};
#pragma unroll 1
    for (int k = 0; k < 9; ++k) {
        b16x8 a0 = wABv[(k * 8 + 0) * 64 + lane];   // ks0, mt0..3
        b16x8 a1 = wABv[(k * 8 + 1) * 64 + lane];
        b16x8 a2 = wABv[(k * 8 + 2) * 64 + lane];
        b16x8 a3 = wABv[(k * 8 + 3) * 64 + lane];
        b16x8 a4 = wABv[(k * 8 + 4) * 64 + lane];   // ks1, mt0..3
        b16x8 a5 = wABv[(k * 8 + 5) * 64 + lane];
        b16x8 a6 = wABv[(k * 8 + 6) * 64 + lane];
        b16x8 a7 = wABv[(k * 8 + 7) * 64 + lane];

        float dy = omL[(2 * k) * 64 + px];
        float dx = omL[(2 * k + 1) * 64 + px];
        float mo = omL[(18 + k) * 64 + px];
        float m  = 1.f / (1.f + __expf(-mo));
        int ky = k / 3, kx = k - ky * 3;
        float ys = (float)(h - 1 + ky) + dy;
        float xs = (float)(w - 1 + kx) + dx;
        float y0f = floorf(ys), x0f = floorf(xs);
        float ly = ys - y0f, lx = xs - x0f;
        float hy = 1.f - ly, hx = 1.f - lx;
        int y0 = (int)y0f, x0 = (int)x0f;
        int y1 = y0 + 1, x1 = x0 + 1;
        bool vy0 = (y0 >= 0) && (y0 < Hs);
        bool vy1 = (y1 >= 0) && (y1 < Hs);
        bool vx0 = (x0 >= 0) && (x0 < Ws);
        bool vx1 = (x1 >= 0) && (x1 < Ws);
        float w00 = (vy0 && vx0) ? m * hy * hx : 0.f;
        float w01 = (vy0 && vx1) ? m * hy * lx : 0.f;
        float w10 = (vy1 && vx0) ? m * ly * hx : 0.f;
        float w11 = (vy1 && vx1) ? m * ly * lx : 0.f;
        int y0c = min(max(y0, 0), Hs - 1), y1c = min(max(y1, 0), Hs - 1);
        int x0c = min(max(x0, 0), Ws - 1), x1c = min(max(x1, 0), Ws - 1);
        int o00 = y0c * Ws + x0c, o01 = y0c * Ws + x1c;
        int o10 = y1c * Ws + x0c, o11 = y1c * Ws + x1c;

        // ---- batched gathers: all 64 issues precede all uses ----
        const float* p00 = xg + o00;
        const float* p01 = xg + o01;
        const float* p10 = xg + o10;
        const float* p11 = xg + o11;
        float c00[16], c01[16], c10[16], c11[16];
#pragma unroll
        for (int i = 0; i < 16; ++i) c00[i] = p00[i * PLANE];
#pragma unroll
        for (int i = 0; i < 16; ++i) c01[i] = p01[i * PLANE];
#pragma unroll
        for (int i = 0; i < 16; ++i) c10[i] = p10[i * PLANE];
#pragma unroll
        for (int i = 0; i < 16; ++i) c11[i] = p11[i * PLANE];

        b16x8 v0, v1;
#pragma unroll
        for (int i = 0; i < 16; ++i) {
            float vv = c00[i] * w00 + c01[i] * w01 + c10[i] * w10 + c11[i] * w11;
            if (i < 8) v0[i] = (__bf16)vv; else v1[i - 8] = (__bf16)vv;
        }
        int wb = (k & 1) * 4608 + px * 72 + g * 16;
        *(b16x8*)&sS[wb]     = v0;
        *(b16x8*)&sS[wb + 8] = v1;
        __syncthreads();

        int rbase = (k & 1) * 4608 + (g * 16 + n) * 72 + kg * 8;
        b16x8 bf0 = *(const b16x8*)&sS[rbase];
        b16x8 bf1 = *(const b16x8*)&sS[rbase + 32];
        acc0 = __builtin_amdgcn_mfma_f32_16x16x32_bf16(a0, bf0, acc0, 0, 0, 0);
        acc1 = __builtin_amdgcn_mfma_f32_16x16x32_bf16(a1, bf0, acc1, 0, 0, 0);
        acc2 = __builtin_amdgcn_mfma_f32_16x16x32_bf16(a2, bf0, acc2, 0, 0, 0);
        acc3 = __builtin_amdgcn_mfma_f32_16x16x32_bf16(a3, bf0, acc3, 0, 0, 0);
        acc0 = __builtin_amdgcn_mfma_f32_16x16x32_bf16(a4, bf1, acc0, 0, 0, 0);
        acc1 = __builtin_amdgcn_mfma_f32_16x16x32_bf16(a5, bf1, acc1, 0, 0, 0);
        acc2 = __builtin_amdgcn_mfma_f32_16x16x32_bf16(a6, bf1, acc2, 0, 0, 0);
        acc3 = __builtin_amdgcn_mfma_f32_16x16x32_bf16(a7, bf1, acc3, 0, 0, 0);
    }

    // epilogue: C layout row=o-within-tile=(kg*4+r), col=n -> px strip g*16+n
    int ob = b * (COUT_ * PLANE) + rblk + g * 16 + n;
#pragma unroll
    for (int rg = 0; rg < 4; ++rg) { int o =      kg * 4 + rg; out[ob + o * PLANE] = acc0[rg] + bias[o]; }
#pragma unroll
    for (int rg = 0; rg < 4; ++rg) { int o = 16 + kg * 4 + rg; out[ob + o * PLANE] = acc1[rg] + bias[o]; }
#pragma unroll
    for (int rg = 0; rg < 4; ++rg) { int o = 32 + kg * 4 + rg; out[ob + o * PLANE] = acc2[rg] + bias[o]; }
#pragma unroll
    for (int rg = 0; rg < 4; ++rg) { int o = 48 + kg * 4 + rg; out[ob + o * PLANE] = acc3[rg] + bias[o]; }
}

extern "C" void kernel_launch(void* const* d_in, const int* in_sizes, int n_in,
                              void* d_out, int out_size, void* d_ws, size_t ws_size,
                              hipStream_t stream) {
    const float* x      = (const float*)d_in[0];
    const float* w_off  = (const float*)d_in[1];
    const float* b_off  = (const float*)d_in[2];
    const float* weight = (const float*)d_in[3];
    const float* bias   = (const float*)d_in[4];
    float* out = (float*)d_out;

    char* ws = (char*)d_ws;
    __bf16* wAB = (__bf16*)ws;             // 73728 B
    __bf16* wAO = (__bf16*)(ws + 73728);   // 36864 B

    prep<<<144, 256, 0, stream>>>(weight, w_off, wAB, wAO);
    deform_mfma<<<NBLK, 256, 0, stream>>>(x, wAO, b_off, wAB, bias, out);
}